// Round 1
// baseline (94.504 us; speedup 1.0000x reference)
//
#include <hip/hip_runtime.h>

// ---------------------------------------------------------------------------
// AtomicLinear == x @ W^T + bias.  M=8192 (B), N=2048 (OUT), K=2048 (IN), fp32.
// Strategy: prepass converts x and W (fp32) to bf16 into d_ws in a
// tiled (128x64) + XOR-swizzled layout; main kernel is the m97-style 128^2
// bf16 MFMA GEMM using global_load_lds (linear dest) + swizzled ds_read_b128.
// ---------------------------------------------------------------------------

typedef short     bf16x8   __attribute__((ext_vector_type(8)));
typedef unsigned short ushort8 __attribute__((ext_vector_type(8)));
typedef float     f32x4    __attribute__((ext_vector_type(4)));

static constexpr int M = 8192, N = 2048, K = 2048;
static constexpr int BM = 128, BN = 128, BK = 64;
static constexpr int KT = K / BK;            // 32 K-tiles
static constexpr int TILE_ELEMS = BM * BK;   // 8192 bf16 per tile (16 KB)

// round-to-nearest-even fp32 -> bf16 (inputs are finite normals)
__device__ __forceinline__ unsigned short f2bf(float f) {
    unsigned u = __float_as_uint(f);
    u += 0x7fffu + ((u >> 16) & 1u);
    return (unsigned short)(u >> 16);
}

// Convert fp32 [rows x K] row-major into tiled + swizzled bf16.
// Tile (rt, kt): base = (rt*KT + kt) * TILE_ELEMS.
// Within tile, element (r, c) [r<128, c<64] lives at r*64 + (c ^ ((r&7)<<3)).
// One thread handles one 8-element (16 B) k-chunk: chunk (r, c0) -> slot c0^(r&7).
__global__ void conv_kernel(const float* __restrict__ src,
                            unsigned short* __restrict__ dst) {
    int g   = blockIdx.x * blockDim.x + threadIdx.x;
    int c0  = g & 7;
    int t   = g >> 3;
    int r   = t & 127;
    int tile = t >> 7;           // rt*KT + kt
    int kt  = tile & (KT - 1);
    int rt  = tile >> 5;         // KT == 32

    const float* p = src + ((size_t)(rt * 128 + r)) * K + (kt * 64 + c0 * 8);
    float4 v0 = *(const float4*)(p);
    float4 v1 = *(const float4*)(p + 4);
    ushort8 o;
    o[0] = f2bf(v0.x); o[1] = f2bf(v0.y); o[2] = f2bf(v0.z); o[3] = f2bf(v0.w);
    o[4] = f2bf(v1.x); o[5] = f2bf(v1.y); o[6] = f2bf(v1.z); o[7] = f2bf(v1.w);

    size_t off = (size_t)tile * TILE_ELEMS + r * 64 + ((c0 ^ (r & 7)) * 8);
    *(ushort8*)(dst + off) = o;
}

#define GL_LDS16(gsrc, ldst)                                                    \
    __builtin_amdgcn_global_load_lds(                                           \
        (const __attribute__((address_space(1))) void*)(gsrc),                  \
        (__attribute__((address_space(3))) void*)(ldst), 16, 0, 0)

// 128x128 tile, 4 waves (2x2), each wave computes 64x64 via 4x4 x 16x16x32 MFMA.
__global__ void gemm_bf16(const unsigned short* __restrict__ xa,   // tiled+swz A
                          const unsigned short* __restrict__ wb,   // tiled+swz B
                          const float* __restrict__ bias,
                          float* __restrict__ out) {
    __shared__ short smem[2 * TILE_ELEMS];   // 32 KB: A tile then B tile
    short* sA = smem;
    short* sB = smem + TILE_ELEMS;

    const int tid  = threadIdx.x;            // 0..255
    const int lane = tid & 63;
    const int wid  = tid >> 6;
    const int wr   = wid >> 1;               // wave row 0..1
    const int wc   = wid & 1;                // wave col 0..1
    const int fr   = lane & 15;              // fragment row/col within 16
    const int fq   = lane >> 4;              // 0..3 (k-chunk / acc row group)

    const int bx = blockIdx.x;               // 1024 blocks
    const int mt = bx >> 4;                  // 0..63
    const int nt = bx & 15;                  // 0..15

    const unsigned short* aTiles = xa + (size_t)mt * KT * TILE_ELEMS;
    const unsigned short* bTiles = wb + (size_t)nt * KT * TILE_ELEMS;

    f32x4 acc[4][4];
#pragma unroll
    for (int i = 0; i < 4; ++i)
#pragma unroll
        for (int j = 0; j < 4; ++j)
            acc[i][j] = f32x4{0.f, 0.f, 0.f, 0.f};

    // per-lane LDS read offsets (element units); swizzle slot = cb ^ (row&7)
    // A frag (mi, ks): row = wr*64 + mi*16 + fr, chunk col cb = ks*4 + fq
    int aRow[4], bRow[4];
#pragma unroll
    for (int i = 0; i < 4; ++i) {
        aRow[i] = wr * 64 + i * 16 + fr;
        bRow[i] = wc * 64 + i * 16 + fr;
    }

    for (int kt = 0; kt < KT; ++kt) {
        __syncthreads();  // previous tile's reads complete before overwrite
        {
            const char* gA = (const char*)(aTiles + (size_t)kt * TILE_ELEMS) + tid * 16;
            const char* gB = (const char*)(bTiles + (size_t)kt * TILE_ELEMS) + tid * 16;
            char* lA = (char*)sA + tid * 16;
            char* lB = (char*)sB + tid * 16;
#pragma unroll
            for (int i = 0; i < 4; ++i) {
                GL_LDS16(gA + i * 4096, lA + i * 4096);
                GL_LDS16(gB + i * 4096, lB + i * 4096);
            }
        }
        __syncthreads();  // implies vmcnt(0): tile resident

#pragma unroll
        for (int ks = 0; ks < 2; ++ks) {
            const int cb = ks * 4 + fq;      // 16B chunk column index, 0..7
            bf16x8 af[4], bf[4];
#pragma unroll
            for (int mi = 0; mi < 4; ++mi) {
                int r = aRow[mi];
                af[mi] = *(const bf16x8*)(sA + r * 64 + ((cb ^ (r & 7)) << 3));
            }
#pragma unroll
            for (int ni = 0; ni < 4; ++ni) {
                int r = bRow[ni];
                bf[ni] = *(const bf16x8*)(sB + r * 64 + ((cb ^ (r & 7)) << 3));
            }
#pragma unroll
            for (int mi = 0; mi < 4; ++mi)
#pragma unroll
                for (int ni = 0; ni < 4; ++ni)
                    acc[mi][ni] = __builtin_amdgcn_mfma_f32_16x16x32_bf16(
                        af[mi], bf[ni], acc[mi][ni], 0, 0, 0);
        }
    }

    // Epilogue. C/D layout (m89/m91): col = lane&15, row = (lane>>4)*4 + reg.
    const int row0 = mt * 128 + wr * 64;
    const int col0 = nt * 128 + wc * 64;
#pragma unroll
    for (int ni = 0; ni < 4; ++ni) {
        int gn = col0 + ni * 16 + fr;
        float bv = bias[gn];
#pragma unroll
        for (int mi = 0; mi < 4; ++mi) {
            int gm = row0 + mi * 16 + fq * 4;
#pragma unroll
            for (int r = 0; r < 4; ++r)
                out[(size_t)(gm + r) * N + gn] = acc[mi][ni][r] + bv;
        }
    }
}

// Correct-but-slow fp32 fallback if workspace is too small for bf16 copies.
__global__ void fallback_gemm(const float* __restrict__ x, const float* __restrict__ w,
                              const float* __restrict__ bias, float* __restrict__ out) {
    __shared__ float As[64][17];
    __shared__ float Bs[64][17];
    int tx = threadIdx.x & 15, ty = threadIdx.x >> 4;
    int m0 = blockIdx.y * 64, n0 = blockIdx.x * 64;
    float acc[4][4] = {};
    for (int k0 = 0; k0 < K; k0 += 16) {
#pragma unroll
        for (int i = 0; i < 4; ++i) {
            int idx = threadIdx.x + i * 256;
            int rr = idx >> 4, cc = idx & 15;
            As[rr][cc] = x[(size_t)(m0 + rr) * K + k0 + cc];
            Bs[rr][cc] = w[(size_t)(n0 + rr) * K + k0 + cc];
        }
        __syncthreads();
#pragma unroll
        for (int kk = 0; kk < 16; ++kk) {
            float a[4], b[4];
#pragma unroll
            for (int i = 0; i < 4; ++i) a[i] = As[ty * 4 + i][kk];
#pragma unroll
            for (int j = 0; j < 4; ++j) b[j] = Bs[tx * 4 + j][kk];
#pragma unroll
            for (int i = 0; i < 4; ++i)
#pragma unroll
                for (int j = 0; j < 4; ++j) acc[i][j] += a[i] * b[j];
        }
        __syncthreads();
    }
#pragma unroll
    for (int i = 0; i < 4; ++i)
#pragma unroll
        for (int j = 0; j < 4; ++j) {
            int gm = m0 + ty * 4 + i, gn = n0 + tx * 4 + j;
            out[(size_t)gm * N + gn] = acc[i][j] + bias[gn];
        }
}

extern "C" void kernel_launch(void* const* d_in, const int* in_sizes, int n_in,
                              void* d_out, int out_size, void* d_ws, size_t ws_size,
                              hipStream_t stream) {
    const float* x    = (const float*)d_in[0];
    const float* w    = (const float*)d_in[1];
    const float* bias = (const float*)d_in[2];
    float* out        = (float*)d_out;

    const size_t needA = (size_t)M * K * sizeof(unsigned short);  // 33.5 MB
    const size_t needB = (size_t)N * K * sizeof(unsigned short);  //  8.4 MB

    if (ws_size >= needA + needB) {
        unsigned short* xa = (unsigned short*)d_ws;
        unsigned short* wb = xa + (size_t)M * K;
        conv_kernel<<<(M * K / 8) / 256, 256, 0, stream>>>(x, xa);
        conv_kernel<<<(N * K / 8) / 256, 256, 0, stream>>>(w, wb);
        gemm_bf16<<<(M / BM) * (N / BN), 256, 0, stream>>>(xa, wb, bias, out);
    } else {
        dim3 grid(N / 64, M / 64);
        fallback_gemm<<<grid, 256, 0, stream>>>(x, w, bias, out);
    }
}

// Round 2
// 89.547 us; speedup vs baseline: 1.0554x; 1.0554x over previous
//
#include <hip/hip_runtime.h>

// ---------------------------------------------------------------------------
// AtomicLinear == x @ W^T + bias.  M=8192, N=2048, K=2048, fp32 in/out.
// R2: 256x256 tile, BK=32, 4-buffer ring LDS (128 KiB), counted vmcnt(8)
// pipeline (never drains to 0 in the loop), raw s_barrier, setprio around
// MFMA, inline-asm ds_read_b128 (+lgkmcnt(0)+sched_barrier per rule #18).
// Prepass bakes a row-pair XOR swizzle into the bf16 tile image so
// global_load_lds stays linear and ds_read_b128 is bank-conflict-free.
// ---------------------------------------------------------------------------

typedef short          bf16x8  __attribute__((ext_vector_type(8)));
typedef unsigned short ushort8 __attribute__((ext_vector_type(8)));
typedef float          f32x4   __attribute__((ext_vector_type(4)));

static constexpr int Mdim = 8192, Ndim = 2048, Kdim = 2048;
static constexpr int BKt  = 32;                     // K per tile
static constexpr int KT2  = Kdim / BKt;             // 64 K-tiles
static constexpr int TILE_BYTES = 256 * BKt * 2;    // 16384 B per 256x32 tile
static constexpr int BUF_BYTES  = 2 * TILE_BYTES;   // 32768 B (A+B per buffer)

__device__ __forceinline__ unsigned short f2bf(float f) {
    unsigned u = __float_as_uint(f);
    u += 0x7fffu + ((u >> 16) & 1u);
    return (unsigned short)(u >> 16);
}

// ---------------------------------------------------------------------------
// Prepass: fp32 [R][2048] row-major -> bf16 tiles of 256 rows x 32 cols.
// Tile (rt, kt) base elem = (rt*64 + kt) * 8192.  Within a tile, the image is
// 128 lines x 128 B; line L holds rows {2L, 2L+1}; the 16B chunk for
// (row r, cols c0*8..c0*8+7) sits at slot = (c0 | ((r&1)<<2)) ^ ((r>>1)&7).
// This is exactly the LDS image gemm2 wants (linear global_load_lds dest).
// ---------------------------------------------------------------------------
__global__ void conv2(const float* __restrict__ src, unsigned short* __restrict__ dst) {
    int g    = blockIdx.x * 256 + threadIdx.x;   // one thread per 16B chunk
    int idx  = g & 1023;                          // chunk within tile
    int tile = g >> 10;
    int line = idx >> 3, slot = idx & 7;
    int cs   = slot ^ (line & 7);                 // = chunk | (sub<<2)
    int r    = 2 * line + (cs >> 2);
    int c0   = (cs & 3) << 3;
    int kt   = tile & 63, rt = tile >> 6;

    const float* p = src + (size_t)(rt * 256 + r) * 2048 + kt * 32 + c0;
    float4 v0 = *(const float4*)p;
    float4 v1 = *(const float4*)(p + 4);
    ushort8 o;
    o[0] = f2bf(v0.x); o[1] = f2bf(v0.y); o[2] = f2bf(v0.z); o[3] = f2bf(v0.w);
    o[4] = f2bf(v1.x); o[5] = f2bf(v1.y); o[6] = f2bf(v1.z); o[7] = f2bf(v1.w);
    *(ushort8*)(dst + (size_t)g * 8) = o;         // fully linear/coalesced write
}

#define GL_LDS16(gsrc, ldst)                                                    \
    __builtin_amdgcn_global_load_lds(                                           \
        (const __attribute__((address_space(1))) void*)(gsrc),                  \
        (__attribute__((address_space(3))) void*)(ldst), 16, 0, 0)

#define WAITBAR(n)                                                              \
    {                                                                           \
        asm volatile("s_waitcnt vmcnt(" #n ")" ::: "memory");                   \
        __builtin_amdgcn_s_barrier();                                           \
    }

// One K-tile of compute for one wave: 12 ds_read_b128 + 32 MFMA.
__device__ __forceinline__ void compute_tile(unsigned aA, unsigned bA,
                                             f32x4 acc[8][4]) {
    bf16x8 af[8], bv[4];
#pragma unroll
    for (int mi = 0; mi < 8; ++mi)
        asm volatile("ds_read_b128 %0, %1 offset:%2"
                     : "=v"(af[mi]) : "v"(aA), "i"(mi * 1024));
#pragma unroll
    for (int ni = 0; ni < 4; ++ni)
        asm volatile("ds_read_b128 %0, %1 offset:%2"
                     : "=v"(bv[ni]) : "v"(bA), "i"(ni * 1024));
    asm volatile("s_waitcnt lgkmcnt(0)" ::: "memory");
    __builtin_amdgcn_sched_barrier(0);   // rule #18: keep MFMA below the wait
    __builtin_amdgcn_s_setprio(1);
#pragma unroll
    for (int mi = 0; mi < 8; ++mi)
#pragma unroll
        for (int ni = 0; ni < 4; ++ni)
            acc[mi][ni] = __builtin_amdgcn_mfma_f32_16x16x32_bf16(
                af[mi], bv[ni], acc[mi][ni], 0, 0, 0);
    __builtin_amdgcn_s_setprio(0);
}

// 256x256 block tile, 512 threads (8 waves as 2M x 4N), wave tile 128x64.
__global__ __launch_bounds__(512, 2) void gemm2(
    const unsigned short* __restrict__ xa, const unsigned short* __restrict__ wb,
    const float* __restrict__ bias, float* __restrict__ out) {
    extern __shared__ char smem[];                // 4 x 32 KB ring

    const int tid  = threadIdx.x;
    const int lane = tid & 63, wid = tid >> 6;
    const int wr   = wid >> 2;                    // 0..1
    const int wc   = wid & 3;                     // 0..3
    const int fr   = lane & 15, fq = lane >> 4;
    const int l3   = fr >> 1;
    const int slot = (fq | ((fr & 1) << 2)) ^ l3; // swizzle slot (const per lane)

    const int bid = blockIdx.x;                   // 256 blocks = 1/CU
    const int nt  = bid & 7;                      // XCD-local B panel (T1)
    const int mt  = bid >> 3;                     // 0..31

    const char* aT = (const char*)xa + (size_t)mt * KT2 * TILE_BYTES;
    const char* bT = (const char*)wb + (size_t)nt * KT2 * TILE_BYTES;

    const unsigned ldsBase = (unsigned)(size_t)smem;  // low 32b = LDS offset
    const unsigned aAddr0  = ldsBase +
        (unsigned)(((wr * 64 + l3) * 64 + slot * 8) * 2);
    const unsigned bAddr0  = ldsBase + 16384u +
        (unsigned)(((wc * 32 + l3) * 64 + slot * 8) * 2);

    f32x4 acc[8][4];
#pragma unroll
    for (int i = 0; i < 8; ++i)
#pragma unroll
        for (int j = 0; j < 4; ++j)
            acc[i][j] = f32x4{0.f, 0.f, 0.f, 0.f};

#define STAGE(t_)                                                               \
    {                                                                           \
        const char* gA = aT + (size_t)(t_)*TILE_BYTES + tid * 16;               \
        const char* gB = bT + (size_t)(t_)*TILE_BYTES + tid * 16;               \
        char* lb = smem + ((t_) & 3) * BUF_BYTES + tid * 16;                    \
        GL_LDS16(gA, lb);                                                       \
        GL_LDS16(gA + 8192, lb + 8192);                                         \
        GL_LDS16(gB, lb + 16384);                                               \
        GL_LDS16(gB + 8192, lb + 24576);                                        \
    }

    // Prologue: depth-3 prefetch.  12 loads out; wait->8 = tile 0 resident.
    STAGE(0);
    STAGE(1);
    STAGE(2);
    WAITBAR(8);

    // Steady state: issue t+3, compute t, wait tile t+1 (vmcnt never 0 here).
    for (int t = 0; t < KT2 - 3; ++t) {
        STAGE(t + 3);
        const unsigned ba = (unsigned)((t & 3) * BUF_BYTES);
        compute_tile(aAddr0 + ba, bAddr0 + ba, acc);
        WAITBAR(8);
    }
    // Drain: 8 -> 4 -> 0.
    compute_tile(aAddr0 + 1u * BUF_BYTES, bAddr0 + 1u * BUF_BYTES, acc);  // t=61
    WAITBAR(4);
    compute_tile(aAddr0 + 2u * BUF_BYTES, bAddr0 + 2u * BUF_BYTES, acc);  // t=62
    WAITBAR(0);
    compute_tile(aAddr0 + 3u * BUF_BYTES, bAddr0 + 3u * BUF_BYTES, acc);  // t=63

    // Epilogue: C/D layout col = lane&15, row = (lane>>4)*4 + reg.
    const int gcol  = nt * 256 + wc * 64;
    const int grow0 = mt * 256 + wr * 128 + fq * 4;
#pragma unroll
    for (int ni = 0; ni < 4; ++ni) {
        const int cn = gcol + ni * 16 + fr;
        const float bv2 = bias[cn];
#pragma unroll
        for (int mi = 0; mi < 8; ++mi) {
            const int rm = grow0 + mi * 16;
#pragma unroll
            for (int rr = 0; rr < 4; ++rr)
                out[(size_t)(rm + rr) * Ndim + cn] = acc[mi][ni][rr] + bv2;
        }
    }
#undef STAGE
}

// Correct-but-slow fp32 fallback if workspace is too small for bf16 copies.
__global__ void fallback_gemm(const float* __restrict__ x, const float* __restrict__ w,
                              const float* __restrict__ bias, float* __restrict__ out) {
    __shared__ float As[64][17];
    __shared__ float Bs[64][17];
    int tx = threadIdx.x & 15, ty = threadIdx.x >> 4;
    int m0 = blockIdx.y * 64, n0 = blockIdx.x * 64;
    float acc[4][4] = {};
    for (int k0 = 0; k0 < Kdim; k0 += 16) {
#pragma unroll
        for (int i = 0; i < 4; ++i) {
            int idx = threadIdx.x + i * 256;
            int rr = idx >> 4, cc = idx & 15;
            As[rr][cc] = x[(size_t)(m0 + rr) * Kdim + k0 + cc];
            Bs[rr][cc] = w[(size_t)(n0 + rr) * Kdim + k0 + cc];
        }
        __syncthreads();
#pragma unroll
        for (int kk = 0; kk < 16; ++kk) {
            float a[4], b[4];
#pragma unroll
            for (int i = 0; i < 4; ++i) a[i] = As[ty * 4 + i][kk];
#pragma unroll
            for (int j = 0; j < 4; ++j) b[j] = Bs[tx * 4 + j][kk];
#pragma unroll
            for (int i = 0; i < 4; ++i)
#pragma unroll
                for (int j = 0; j < 4; ++j) acc[i][j] += a[i] * b[j];
        }
        __syncthreads();
    }
#pragma unroll
    for (int i = 0; i < 4; ++i)
#pragma unroll
        for (int j = 0; j < 4; ++j) {
            int gm = m0 + ty * 4 + i, gn = n0 + tx * 4 + j;
            out[(size_t)gm * Ndim + gn] = acc[i][j] + bias[gn];
        }
}

extern "C" void kernel_launch(void* const* d_in, const int* in_sizes, int n_in,
                              void* d_out, int out_size, void* d_ws, size_t ws_size,
                              hipStream_t stream) {
    const float* x    = (const float*)d_in[0];
    const float* w    = (const float*)d_in[1];
    const float* bias = (const float*)d_in[2];
    float* out        = (float*)d_out;

    const size_t needA = (size_t)Mdim * Kdim * sizeof(unsigned short);
    const size_t needB = (size_t)Ndim * Kdim * sizeof(unsigned short);

    if (ws_size >= needA + needB) {
        unsigned short* xa = (unsigned short*)d_ws;
        unsigned short* wb = xa + (size_t)Mdim * Kdim;
        // x: 32 rt x 64 kt tiles x 1024 chunks / 256 thr = 8192 blocks
        conv2<<<(Mdim / 256) * KT2 * 1024 / 256, 256, 0, stream>>>(x, xa);
        // w: 8 rt x 64 kt -> 2048 blocks
        conv2<<<(Ndim / 256) * KT2 * 1024 / 256, 256, 0, stream>>>(w, wb);

        (void)hipFuncSetAttribute((const void*)gemm2,
                                  hipFuncAttributeMaxDynamicSharedMemorySize,
                                  4 * BUF_BYTES);
        gemm2<<<(Mdim / 256) * (Ndim / 256), 512, 4 * BUF_BYTES, stream>>>(
            xa, wb, bias, out);
    } else {
        dim3 grid(Ndim / 64, Mdim / 64);
        fallback_gemm<<<grid, 256, 0, stream>>>(x, w, bias, out);
    }
}